// Round 1
// baseline (210.893 us; speedup 1.0000x reference)
//
#include <hip/hip_runtime.h>
#include <hip/hip_bf16.h>
#include <stdint.h>

#define N_ROWS 16384
#define K_DIM  1024
#define N_OUT  4096

#define BM 128
#define BN 128
#define BK 32

typedef __attribute__((ext_vector_type(8))) short short8;
typedef __attribute__((ext_vector_type(4))) float f32x4;
typedef __attribute__((ext_vector_type(4))) __bf16 bf16x4;

// ---------------- fp32 -> bf16 convert (vectorized: float4 in, bf16x4 out) ----
__global__ void cvt_kernel(const float* __restrict__ in, __bf16* __restrict__ out, int n4) {
    int stride = gridDim.x * blockDim.x;
    for (int i = blockIdx.x * blockDim.x + threadIdx.x; i < n4; i += stride) {
        float4 v = reinterpret_cast<const float4*>(in)[i];
        bf16x4 o;
        o[0] = (__bf16)v.x; o[1] = (__bf16)v.y; o[2] = (__bf16)v.z; o[3] = (__bf16)v.w;
        reinterpret_cast<bf16x4*>(out)[i] = o;
    }
}

// ---------------- bf16 MFMA GEMM: out = mask * (x . W^T + b) ------------------
// A = x_bf16 [N_ROWS][K], B = W_bf16 [N_OUT][K]  (both K-contiguous)
__global__ __launch_bounds__(256) void gemm_kernel(
    const __bf16* __restrict__ A,
    const __bf16* __restrict__ B,
    const float*  __restrict__ bias,
    const int*    __restrict__ amask,
    float*        __restrict__ out)
{
    __shared__ __bf16 ldsA[BM][BK];   // 8 KB, linear (global_load_lds dest)
    __shared__ __bf16 ldsB[BN][BK];   // 8 KB

    const int t  = threadIdx.x;
    const int l  = t & 63;
    const int w  = t >> 6;
    const int wm = w >> 1, wn = w & 1;      // 2x2 wave grid, 64x64 per wave
    const int m0 = blockIdx.y * BM;
    const int n0 = blockIdx.x * BN;

    const int lr = l & 15;                  // fragment row/col lane index
    const int lq = l >> 4;                  // k-group / C row-group
    const int lk = lq * 8;                  // element offset of 8-wide k-run

    f32x4 acc[4][4] = {};

    for (int k0 = 0; k0 < K_DIM; k0 += BK) {
        // Stage A (8 KB) + B (8 KB). Each thread stages 16 B per pass, 2 passes.
        // LDS dest is linear: byte off = p*4096 + t*16  (lane0-of-wave uniform base).
        #pragma unroll
        for (int p = 0; p < 2; ++p) {
            int off = p * 4096 + t * 16;    // byte offset within tile
            int row = off >> 6;             // 64 B per row (32 bf16)
            int col = (off & 63) >> 1;      // element within row
            const __bf16* ga = A + (size_t)(m0 + row) * K_DIM + k0 + col;
            __builtin_amdgcn_global_load_lds(
                (const __attribute__((address_space(1))) void*)ga,
                (__attribute__((address_space(3))) void*)((char*)&ldsA[0][0] + off),
                16, 0, 0);
            const __bf16* gb = B + (size_t)(n0 + row) * K_DIM + k0 + col;
            __builtin_amdgcn_global_load_lds(
                (const __attribute__((address_space(1))) void*)gb,
                (__attribute__((address_space(3))) void*)((char*)&ldsB[0][0] + off),
                16, 0, 0);
        }
        __syncthreads();   // compiler inserts vmcnt(0) drain before s_barrier

        short8 af[4], bf[4];
        #pragma unroll
        for (int mi = 0; mi < 4; ++mi)
            af[mi] = *reinterpret_cast<const short8*>(&ldsA[wm*64 + mi*16 + lr][lk]);
        #pragma unroll
        for (int ni = 0; ni < 4; ++ni)
            bf[ni] = *reinterpret_cast<const short8*>(&ldsB[wn*64 + ni*16 + lr][lk]);

        #pragma unroll
        for (int mi = 0; mi < 4; ++mi)
            #pragma unroll
            for (int ni = 0; ni < 4; ++ni)
                acc[mi][ni] = __builtin_amdgcn_mfma_f32_16x16x32_bf16(
                    af[mi], bf[ni], acc[mi][ni], 0, 0, 0);
        __syncthreads();
    }

    // Epilogue: bias + row mask. C/D layout: col = lane&15, row = (lane>>4)*4 + reg.
    float bv[4];
    #pragma unroll
    for (int ni = 0; ni < 4; ++ni) bv[ni] = bias[n0 + wn*64 + ni*16 + lr];

    #pragma unroll
    for (int mi = 0; mi < 4; ++mi) {
        int r0 = m0 + wm*64 + mi*16 + lq*4;
        float km[4];
        #pragma unroll
        for (int r = 0; r < 4; ++r) km[r] = (amask[r0 + r] != 0) ? 1.0f : 0.0f;
        #pragma unroll
        for (int ni = 0; ni < 4; ++ni) {
            int c = n0 + wn*64 + ni*16 + lr;
            #pragma unroll
            for (int r = 0; r < 4; ++r)
                out[(size_t)(r0 + r) * N_OUT + c] = km[r] * (acc[mi][ni][r] + bv[ni]);
        }
    }
}

// ---------------- naive fp32 fallback (only if ws too small) ------------------
__global__ void naive_kernel(const float* __restrict__ x, const float* __restrict__ W,
                             const float* __restrict__ bias, const int* __restrict__ amask,
                             float* __restrict__ out) {
    int c = blockIdx.x * blockDim.x + threadIdx.x;
    int r = blockIdx.y;
    if (c >= N_OUT) return;
    if (amask[r] == 0) { out[(size_t)r * N_OUT + c] = 0.0f; return; }
    const float* xr = x + (size_t)r * K_DIM;
    const float* wr = W + (size_t)c * K_DIM;
    float s = 0.0f;
    for (int k = 0; k < K_DIM; ++k) s += xr[k] * wr[k];
    out[(size_t)r * N_OUT + c] = s + bias[c];
}

extern "C" void kernel_launch(void* const* d_in, const int* in_sizes, int n_in,
                              void* d_out, int out_size, void* d_ws, size_t ws_size,
                              hipStream_t stream) {
    const float* x     = (const float*)d_in[0];
    const int*   amask = (const int*)d_in[1];
    const float* W     = (const float*)d_in[2];
    const float* bias  = (const float*)d_in[3];
    float*       out   = (float*)d_out;

    const size_t xb_bytes = (size_t)N_ROWS * K_DIM * 2;   // 32 MB
    const size_t wb_bytes = (size_t)N_OUT  * K_DIM * 2;   //  8 MB

    if (ws_size < xb_bytes + wb_bytes) {
        dim3 g((N_OUT + 255) / 256, N_ROWS);
        naive_kernel<<<g, 256, 0, stream>>>(x, W, bias, amask, out);
        return;
    }

    __bf16* xb = (__bf16*)d_ws;
    __bf16* wb = (__bf16*)((char*)d_ws + xb_bytes);

    cvt_kernel<<<2048, 256, 0, stream>>>(x, xb, N_ROWS * K_DIM / 4);
    cvt_kernel<<<1024, 256, 0, stream>>>(W, wb, N_OUT * K_DIM / 4);

    dim3 grid(N_OUT / BN, N_ROWS / BM);   // 32 x 128 tiles
    gemm_kernel<<<grid, 256, 0, stream>>>(xb, wb, bias, amask, out);
}

// Round 2
// 205.155 us; speedup vs baseline: 1.0280x; 1.0280x over previous
//
#include <hip/hip_runtime.h>
#include <hip/hip_bf16.h>
#include <stdint.h>

#define N_ROWS 16384
#define K_DIM  1024
#define N_OUT  4096
#define NKT    32              // K_DIM / 32

typedef __attribute__((ext_vector_type(8))) short short8;
typedef __attribute__((ext_vector_type(4))) float f32x4;
typedef __attribute__((ext_vector_type(4))) __bf16 bf16x4;

// ---------------- fp32 -> bf16 convert ----------------------------------------
__global__ void cvt_kernel(const float* __restrict__ in, __bf16* __restrict__ out, int n4) {
    int stride = gridDim.x * blockDim.x;
    for (int i = blockIdx.x * blockDim.x + threadIdx.x; i < n4; i += stride) {
        float4 v = reinterpret_cast<const float4*>(in)[i];
        bf16x4 o;
        o[0] = (__bf16)v.x; o[1] = (__bf16)v.y; o[2] = (__bf16)v.z; o[3] = (__bf16)v.w;
        reinterpret_cast<bf16x4*>(out)[i] = o;
    }
}

// ---------------- 256x256-tile phase-split bf16 MFMA GEMM ---------------------
// A = x_bf16 [N_ROWS][K], B = W_bf16 [N_OUT][K]. out = mask * (A.B^T + bias).
// 8 waves (2M x 4N), per-wave 128x64 output. BK=32, triple-buffered LDS,
// stage kt+2 while computing kt, counted vmcnt(4) once per K-tile.
// LDS holds MFMA fragments contiguously (frag-linear): frag f of a tile at
// byte f*1024 + lane*16; the global_load_lds SOURCE is permuted to match
// (linear LDS dest + per-lane gather source). ds_read_b128 is then
// lane-consecutive -> conflict-free, base + immediate-offset addressing.

#define GLL(SRC, DSTOFF)                                                       \
    __builtin_amdgcn_global_load_lds(                                          \
        (const __attribute__((address_space(1))) void*)(SRC),                  \
        (__attribute__((address_space(3))) void*)(ldsc + (DSTOFF)), 16, 0, 0)

// buffer sb layout (bytes): A tile at sb*32768 (16 KB), B tile at +16384.
#define STAGE_A(sb, kt_) do {                                                  \
    GLL(pA0 + (size_t)(kt_) * 32, (sb)*32768 + t*16);                          \
    GLL(pA1 + (size_t)(kt_) * 32, (sb)*32768 + 8192 + t*16); } while (0)
#define STAGE_B(sb, kt_) do {                                                  \
    GLL(pB0 + (size_t)(kt_) * 32, (sb)*32768 + 16384 + t*16);                  \
    GLL(pB1 + (size_t)(kt_) * 32, (sb)*32768 + 16384 + 8192 + t*16); } while (0)

// One K-tile (two phases of 16 MFMA). buf/sb are compile-time constants.
#define KTILE(buf, sb, stk, DO_STAGE, VMC)                                     \
  {                                                                            \
    const short* aB = lds_all + (buf) * 16384;                                 \
    const short* bB = aB + 8192;                                               \
    short8 af[4], bfr[4];                                                      \
    _Pragma("unroll") for (int m = 0; m < 4; ++m)                              \
      af[m] = *(const short8*)(aB + (wm*8 + m)*512 + l*8);                     \
    _Pragma("unroll") for (int n = 0; n < 4; ++n)                              \
      bfr[n] = *(const short8*)(bB + (wn*4 + n)*512 + l*8);                    \
    if (DO_STAGE) STAGE_A(sb, stk);                                            \
    __builtin_amdgcn_s_barrier();                                              \
    __builtin_amdgcn_s_setprio(1);                                            \
    _Pragma("unroll") for (int m = 0; m < 4; ++m)                              \
      _Pragma("unroll") for (int n = 0; n < 4; ++n)                            \
        acc[m][n] = __builtin_amdgcn_mfma_f32_16x16x32_bf16(                   \
            af[m], bfr[n], acc[m][n], 0, 0, 0);                                \
    __builtin_amdgcn_s_setprio(0);                                            \
    __builtin_amdgcn_s_barrier();                                              \
    _Pragma("unroll") for (int m = 0; m < 4; ++m)                              \
      af[m] = *(const short8*)(aB + (wm*8 + 4 + m)*512 + l*8);                 \
    if (DO_STAGE) STAGE_B(sb, stk);                                            \
    __builtin_amdgcn_s_barrier();                                              \
    __builtin_amdgcn_s_setprio(1);                                            \
    _Pragma("unroll") for (int m = 0; m < 4; ++m)                              \
      _Pragma("unroll") for (int n = 0; n < 4; ++n)                            \
        acc[4 + m][n] = __builtin_amdgcn_mfma_f32_16x16x32_bf16(               \
            af[m], bfr[n], acc[4 + m][n], 0, 0, 0);                            \
    __builtin_amdgcn_s_setprio(0);                                            \
    asm volatile("s_waitcnt vmcnt(" VMC ")" ::: "memory");                     \
    __builtin_amdgcn_s_barrier();                                              \
  }

__global__ __launch_bounds__(512, 2) void gemm_kernel(
    const __bf16* __restrict__ A,
    const __bf16* __restrict__ B,
    const float*  __restrict__ bias,
    const int*    __restrict__ amask,
    float*        __restrict__ out)
{
    __shared__ short lds_all[49152];   // 96 KB: 3 bufs x (A 16KB + B 16KB)

    const int t  = threadIdx.x;
    const int l  = t & 63;
    const int w  = t >> 6;             // wave 0..7
    const int wm = w >> 2;             // 0..1  (row half)
    const int wn = w & 3;              // 0..3  (col quarter)

    // XCD-bijective swizzle: 1024 blocks, 128 per XCD; within an XCD walk
    // column-major over its 8x16 tile sub-grid for W-panel reuse.
    const int bid = blockIdx.x;
    const int xcd = bid & 7;
    const int c   = bid >> 3;          // 0..127
    const int tn  = c >> 3;            // 0..15
    const int tm  = xcd * 8 + (c & 7); // 0..63
    const int m0  = tm * 256;
    const int n0  = tn * 256;

    // Frag-linear staging sources: thread t stages the 16B that lane (t&63)
    // of fragment (pass*8 + t/64) will consume.
    const int rA  = (w << 4) + (t & 15);       // frag row for pass 0
    const int kg8 = ((t >> 4) & 3) * 8;        // k-group offset
    const __bf16* pA0 = A + (size_t)(m0 + rA) * K_DIM + kg8;
    const __bf16* pA1 = pA0 + (size_t)128 * K_DIM;
    const __bf16* pB0 = B + (size_t)(n0 + rA) * K_DIM + kg8;
    const __bf16* pB1 = pB0 + (size_t)128 * K_DIM;
    char* ldsc = (char*)lds_all;

    f32x4 acc[8][4] = {};

    // Prologue: stage kt0 -> buf0, kt1 -> buf1; wait kt0 (4 newest = kt1 stay).
    STAGE_A(0, 0); STAGE_B(0, 0);
    STAGE_A(1, 1); STAGE_B(1, 1);
    asm volatile("s_waitcnt vmcnt(4)" ::: "memory");
    __builtin_amdgcn_s_barrier();

    // Main loop: kt = 0..29, buffers rotate 0,1,2; stage kt+2 -> buf (kt+2)%3.
#pragma unroll 1
    for (int j = 0; j < 10; ++j) {
        const int kt = j * 3;
        KTILE(0, 2, kt + 2, true, "4")
        KTILE(1, 0, kt + 3, true, "4")
        KTILE(2, 1, kt + 4, true, "4")
    }
    // Tails: kt=30 (buf0), kt=31 (buf1), no staging.
    KTILE(0, 0, 0, false, "0")
    KTILE(1, 0, 0, false, "0")

    // Epilogue: bias + row mask. C/D: col = l&15, row = (l>>4)*4 + reg.
    const int lr = l & 15;
    const int lq = l >> 4;
    float bv[4];
#pragma unroll
    for (int n = 0; n < 4; ++n) bv[n] = bias[n0 + wn*64 + n*16 + lr];

#pragma unroll
    for (int m = 0; m < 8; ++m) {
        const int r0 = m0 + wm*128 + m*16 + lq*4;
        float km[4];
#pragma unroll
        for (int r = 0; r < 4; ++r) km[r] = (amask[r0 + r] != 0) ? 1.0f : 0.0f;
#pragma unroll
        for (int n = 0; n < 4; ++n) {
            const int cc = n0 + wn*64 + n*16 + lr;
#pragma unroll
            for (int r = 0; r < 4; ++r)
                out[(size_t)(r0 + r) * N_OUT + cc] = km[r] * (acc[m][n][r] + bv[n]);
        }
    }
}

// ---------------- naive fp32 fallback (only if ws too small) ------------------
__global__ void naive_kernel(const float* __restrict__ x, const float* __restrict__ W,
                             const float* __restrict__ bias, const int* __restrict__ amask,
                             float* __restrict__ out) {
    int c = blockIdx.x * blockDim.x + threadIdx.x;
    int r = blockIdx.y;
    if (c >= N_OUT) return;
    if (amask[r] == 0) { out[(size_t)r * N_OUT + c] = 0.0f; return; }
    const float* xr = x + (size_t)r * K_DIM;
    const float* wr = W + (size_t)c * K_DIM;
    float s = 0.0f;
    for (int k = 0; k < K_DIM; ++k) s += xr[k] * wr[k];
    out[(size_t)r * N_OUT + c] = s + bias[c];
}

extern "C" void kernel_launch(void* const* d_in, const int* in_sizes, int n_in,
                              void* d_out, int out_size, void* d_ws, size_t ws_size,
                              hipStream_t stream) {
    const float* x     = (const float*)d_in[0];
    const int*   amask = (const int*)d_in[1];
    const float* W     = (const float*)d_in[2];
    const float* bias  = (const float*)d_in[3];
    float*       out   = (float*)d_out;

    const size_t xb_bytes = (size_t)N_ROWS * K_DIM * 2;   // 32 MB
    const size_t wb_bytes = (size_t)N_OUT  * K_DIM * 2;   //  8 MB

    if (ws_size < xb_bytes + wb_bytes) {
        dim3 g((N_OUT + 255) / 256, N_ROWS);
        naive_kernel<<<g, 256, 0, stream>>>(x, W, bias, amask, out);
        return;
    }

    __bf16* xb = (__bf16*)d_ws;
    __bf16* wb = (__bf16*)((char*)d_ws + xb_bytes);

    cvt_kernel<<<2048, 256, 0, stream>>>(x, xb, N_ROWS * K_DIM / 4);
    cvt_kernel<<<1024, 256, 0, stream>>>(W, wb, N_OUT * K_DIM / 4);

    // 64 x 16 = 1024 tiles of 256x256
    gemm_kernel<<<1024, 512, 0, stream>>>(xb, wb, bias, amask, out);
}